// Round 3
// baseline (310.707 us; speedup 1.0000x reference)
//
#include <hip/hip_runtime.h>
#include <hip/hip_bf16.h>
#include <stdint.h>

// Problem constants: N=8, T=200, U=50, E=D=J=512, V=500. M = N*T*U = 80000.
#define JD 512
#define VV 500

typedef short short8 __attribute__((ext_vector_type(8)));
typedef short short4v __attribute__((ext_vector_type(4)));
typedef float floatx4 __attribute__((ext_vector_type(4)));

__device__ inline short f2bf(float f) {
    uint32_t u = __float_as_uint(f);
    uint32_t r = (u + 0x7FFFu + ((u >> 16) & 1u)) >> 16;
    return (short)r;
}

__device__ inline float fast_tanh(float x) {
    // tanh(x) = 1 - 2/(exp(2x)+1); v_exp_f32 is exp2 natively.
    float e = __builtin_amdgcn_exp2f(x * 2.8853900817779268f); // 2*log2(e)
    return 1.0f - 2.0f * __builtin_amdgcn_rcpf(e + 1.0f);
}

// ---------------------------------------------------------------------------
// Kernel 1: projections (cast fp32->bf16 on the fly during staging) PLUS
// W_out cast/pad handled by 16 extra blocks of the same grid (bx >= 17).
// Grid: dim3(21, 4). bx<13: enc (M=1600). 13<=bx<17: dec (M=400). bx>=17: Wb.
// LDS row stride 72 shorts (+4 banks/row): b128 frag reads at 8-phase min.
// ---------------------------------------------------------------------------
#define PST 72
__global__ __launch_bounds__(256) void proj_gemm(
    const float* __restrict__ enc, const float* __restrict__ dec,
    const float* __restrict__ Wenc, const float* __restrict__ Wdec,
    const float* __restrict__ Wout,
    const float* __restrict__ b_enc, const float* __restrict__ b_dec,
    float* __restrict__ enc_p, float* __restrict__ dec_p,
    short* __restrict__ Wb)
{
    __shared__ short As[128 * PST];
    __shared__ short Bs[128 * PST];
    int bx = blockIdx.x, by = blockIdx.y;
    int tid = threadIdx.x;

    if (bx >= 17) {
        // ---- Wb cast path: 16 blocks x 16384 elems (512x512, zero rows >=500)
        int wblk = (bx - 17) * 4 + by;
        int base = wblk * 16384;
        #pragma unroll
        for (int t = 0; t < 16; t++) {
            int i = base + t * 1024 + tid * 4;
            int row = i >> 9;
            short4v o;
            if (row < VV) {
                float4 v = *(const float4*)(Wout + (size_t)row * JD + (i & 511));
                o[0] = f2bf(v.x); o[1] = f2bf(v.y);
                o[2] = f2bf(v.z); o[3] = f2bf(v.w);
            } else {
                o[0] = 0; o[1] = 0; o[2] = 0; o[3] = 0;
            }
            *(short4v*)(Wb + i) = o;
        }
        return;
    }

    const float* A; const float* W; const float* bias; float* C; int M;
    if (bx < 13) { A = enc; W = Wenc; bias = b_enc; C = enc_p; M = 1600; }
    else { bx -= 13; A = dec; W = Wdec; bias = b_dec; C = dec_p; M = 400; }

    int lane = tid & 63, wv = tid >> 6;
    int wm = wv >> 1, wn = wv & 1;
    int l16 = lane & 15, q4 = lane >> 4;

    int r = tid >> 1, h = tid & 1;
    int m_st = bx * 128 + r;
    bool valid = m_st < M;

    floatx4 acc[4][4];
    #pragma unroll
    for (int a = 0; a < 4; a++)
        #pragma unroll
        for (int b = 0; b < 4; b++) acc[a][b] = (floatx4){0.f, 0.f, 0.f, 0.f};

    for (int kk = 0; kk < 8; kk++) {
        int k0 = kk * 64;
        __syncthreads();
        {
            const float* pa = A + (size_t)m_st * JD + k0 + h * 32;
            const float* pb = W + (size_t)(by * 128 + r) * JD + k0 + h * 32;
            short* da = &As[r * PST + h * 32];
            short* db = &Bs[r * PST + h * 32];
            #pragma unroll
            for (int t = 0; t < 8; t++) {
                float4 va = valid ? *(const float4*)(pa + t * 4)
                                  : (float4){0.f, 0.f, 0.f, 0.f};
                float4 vb = *(const float4*)(pb + t * 4);
                short4v oa, ob;
                oa[0] = f2bf(va.x); oa[1] = f2bf(va.y);
                oa[2] = f2bf(va.z); oa[3] = f2bf(va.w);
                ob[0] = f2bf(vb.x); ob[1] = f2bf(vb.y);
                ob[2] = f2bf(vb.z); ob[3] = f2bf(vb.w);
                *(short4v*)(da + t * 4) = oa;
                *(short4v*)(db + t * 4) = ob;
            }
        }
        __syncthreads();
        #pragma unroll
        for (int h2 = 0; h2 < 2; h2++) {
            short8 af[4], bf[4];
            #pragma unroll
            for (int im = 0; im < 4; im++)
                af[im] = *(const short8*)&As[(wm * 64 + im * 16 + l16) * PST + h2 * 32 + q4 * 8];
            #pragma unroll
            for (int in = 0; in < 4; in++)
                bf[in] = *(const short8*)&Bs[(wn * 64 + in * 16 + l16) * PST + h2 * 32 + q4 * 8];
            #pragma unroll
            for (int im = 0; im < 4; im++)
                #pragma unroll
                for (int in = 0; in < 4; in++)
                    acc[im][in] = __builtin_amdgcn_mfma_f32_16x16x32_bf16(
                        af[im], bf[in], acc[im][in], 0, 0, 0);
        }
    }
    #pragma unroll
    for (int im = 0; im < 4; im++) {
        int mb = bx * 128 + wm * 64 + im * 16 + q4 * 4;
        #pragma unroll
        for (int rr = 0; rr < 4; rr++) {
            int m = mb + rr;
            if (m < M) {
                #pragma unroll
                for (int in = 0; in < 4; in++) {
                    int j = by * 128 + wn * 64 + in * 16 + l16;
                    C[(size_t)m * JD + j] = acc[im][in][rr] + bias[j];
                }
            }
        }
    }
}

// ---------------------------------------------------------------------------
// Kernel 2: FUSED act + vocab GEMM, occupancy-fixed.
// 256 threads (4 waves, wave-grid 1x4 over v), 64-row m-tile, grid 1250.
// LDS = 64 x 520 x 2 = 66,560 B -> 2 blocks/CU; __launch_bounds__(256,2)
// caps combined VGPR+AGPR at 256 so registers don't drop us to 1 block.
// Two independent blocks per CU let phase-1 VALU (tanh) of one overlap
// phase-2 MFMA of the other (m114 co-schedule), and smooth the makespan.
// Each wave owns a disjoint 128-col B panel -> no duplicate Wb L2 reads.
// ---------------------------------------------------------------------------
#define AST 520
__global__ __launch_bounds__(256, 2) void fused_joiner(
    const float* __restrict__ enc_p, const float* __restrict__ dec_p,
    const short* __restrict__ Wb, const float* __restrict__ b_out,
    float* __restrict__ out)
{
    __shared__ short As[64 * AST];   // 66,560 B
    int tid = threadIdx.x;
    int bx = blockIdx.x;

    // ---- Phase 1: act tile (64 m-rows x 512 j) -> LDS as bf16
    {
        int rsub = tid >> 7;            // 0..1
        int jf = (tid & 127) * 4;       // coalesced within each row
        #pragma unroll 4
        for (int pass = 0; pass < 32; pass++) {
            int row = pass * 2 + rsub;
            int m = bx * 64 + row;
            int er = m / 50;            // n*200 + t
            int n  = m / 10000;
            int dr = n * 50 + (m - er * 50);
            float4 e = *(const float4*)(enc_p + (size_t)er * JD + jf);
            float4 d = *(const float4*)(dec_p + (size_t)dr * JD + jf);
            short4v o;
            o[0] = f2bf(fast_tanh(e.x + d.x));
            o[1] = f2bf(fast_tanh(e.y + d.y));
            o[2] = f2bf(fast_tanh(e.z + d.z));
            o[3] = f2bf(fast_tanh(e.w + d.w));
            *(short4v*)&As[row * AST + jf] = o;
        }
    }
    __syncthreads();

    // ---- Phase 2: out[64 x 512] = act x Wb^T, K=512
    int lane = tid & 63, wv = tid >> 6;   // wv = v-panel index 0..3
    int l16 = lane & 15, q4 = lane >> 4;

    floatx4 acc[4][8];
    #pragma unroll
    for (int a = 0; a < 4; a++)
        #pragma unroll
        for (int b = 0; b < 8; b++) acc[a][b] = (floatx4){0.f, 0.f, 0.f, 0.f};

    int abase[4];
    #pragma unroll
    for (int im = 0; im < 4; im++)
        abase[im] = (im * 16 + l16) * AST + q4 * 8;
    int boff[8];
    #pragma unroll
    for (int in = 0; in < 8; in++)
        boff[in] = (wv * 128 + in * 16 + l16) * JD + q4 * 8;

    // B register double-buffer (Wb is L2-resident, 512 KB)
    short8 b0[8], b1[8];
    #pragma unroll
    for (int in = 0; in < 8; in++)
        b0[in] = *(const short8*)(Wb + boff[in]);

    for (int ks = 0; ks < 16; ks += 2) {
        int k1 = (ks + 1) * 32;
        #pragma unroll
        for (int in = 0; in < 8; in++)
            b1[in] = *(const short8*)(Wb + boff[in] + k1);
        {
            int k0 = ks * 32;
            short8 af[4];
            #pragma unroll
            for (int im = 0; im < 4; im++)
                af[im] = *(const short8*)&As[abase[im] + k0];
            #pragma unroll
            for (int im = 0; im < 4; im++)
                #pragma unroll
                for (int in = 0; in < 8; in++)
                    acc[im][in] = __builtin_amdgcn_mfma_f32_16x16x32_bf16(
                        af[im], b0[in], acc[im][in], 0, 0, 0);
        }
        if (ks + 2 < 16) {
            int k2 = (ks + 2) * 32;
            #pragma unroll
            for (int in = 0; in < 8; in++)
                b0[in] = *(const short8*)(Wb + boff[in] + k2);
        }
        {
            short8 af[4];
            #pragma unroll
            for (int im = 0; im < 4; im++)
                af[im] = *(const short8*)&As[abase[im] + k1];
            #pragma unroll
            for (int im = 0; im < 4; im++)
                #pragma unroll
                for (int in = 0; in < 8; in++)
                    acc[im][in] = __builtin_amdgcn_mfma_f32_16x16x32_bf16(
                        af[im], b1[in], acc[im][in], 0, 0, 0);
        }
    }

    // ---- Epilogue: bias + store (m always valid; guard v < 500)
    float bo[8];
    #pragma unroll
    for (int in = 0; in < 8; in++) {
        int v = wv * 128 + in * 16 + l16;
        bo[in] = (v < VV) ? b_out[v] : 0.f;
    }
    #pragma unroll
    for (int im = 0; im < 4; im++) {
        int mb = bx * 64 + im * 16 + q4 * 4;
        #pragma unroll
        for (int rr = 0; rr < 4; rr++) {
            size_t orow = (size_t)(mb + rr) * VV;
            #pragma unroll
            for (int in = 0; in < 8; in++) {
                int v = wv * 128 + in * 16 + l16;
                if (v < VV) out[orow + v] = acc[im][in][rr] + bo[in];
            }
        }
    }
}

// ---------------------------------------------------------------------------
extern "C" void kernel_launch(void* const* d_in, const int* in_sizes, int n_in,
                              void* d_out, int out_size, void* d_ws, size_t ws_size,
                              hipStream_t stream)
{
    const float* enc   = (const float*)d_in[0];
    const float* dec   = (const float*)d_in[1];
    const float* Wenc  = (const float*)d_in[2];
    const float* b_enc = (const float*)d_in[3];
    const float* Wdec  = (const float*)d_in[4];
    const float* b_dec = (const float*)d_in[5];
    const float* Wout  = (const float*)d_in[6];
    const float* b_out = (const float*)d_in[7];
    float* out = (float*)d_out;

    // ws layout (bytes): ~4.6 MB total
    char* ws = (char*)d_ws;
    short* Wb    = (short*)(ws + 0);          //  512*512 bf16 = 524288
    float* enc_p = (float*)(ws + 524288);     // 1600*512 f32  = 3276800
    float* dec_p = (float*)(ws + 3801088);    //  400*512 f32  = 819200

    proj_gemm<<<dim3(21, 4), 256, 0, stream>>>(enc, dec, Wenc, Wdec, Wout,
                                               b_enc, b_dec, enc_p, dec_p, Wb);
    fused_joiner<<<1250, 256, 0, stream>>>(enc_p, dec_p, Wb, b_out, out);
}